// Round 1
// baseline (1735.118 us; speedup 1.0000x reference)
//
#include <hip/hip_runtime.h>
#include <math.h>

#define BATCH 8
#define NPT   2048
#define DIM   32
#define BM    128
#define BK    64
#define TM    8
#define TN    4
#define PAD   4      // LDS row stride = 36 floats: 16B-aligned, spreads banks

struct CtSet {
    const float* X;     // rows side  [BATCH][NPT][DIM]
    const float* Y;     // cols side  [BATCH][NPT][DIM]
    const float* pot;   // potential on cols [BATCH][NPT]
    const float* logw;  // log weight on cols
    const float* qX;    // 0.5*||row||^2
    const float* qY;    // 0.5*||col||^2
    const float* prev;  // previous potential on rows (for averaging), may be null
    float* out;         // [BATCH][NPT]
};
struct CtArgs { CtSet s[4]; int average; };

// out[l] = qX[l] - lse_k( x_l . y_k + (pot[k]+logw[k]-qY[k]) ), optionally 0.5*(prev+.)
__global__ __launch_bounds__(256, 2) void ct_kernel(CtArgs args) {
    const CtSet cs = args.s[blockIdx.y];
    const int batch = blockIdx.z;
    const int row0 = blockIdx.x * BM;

    const float* __restrict__ X    = cs.X + (size_t)batch * NPT * DIM;
    const float* __restrict__ Y    = cs.Y + (size_t)batch * NPT * DIM;
    const float* __restrict__ pot  = cs.pot  + (size_t)batch * NPT;
    const float* __restrict__ logw = cs.logw + (size_t)batch * NPT;
    const float* __restrict__ qX   = cs.qX   + (size_t)batch * NPT;
    const float* __restrict__ qY   = cs.qY   + (size_t)batch * NPT;

    __shared__ float sx[BM][DIM + PAD];
    __shared__ float sy[BK][DIM + PAD];
    __shared__ float st[BK];
    __shared__ float red_m[BM][17];
    __shared__ float red_s[BM][17];

    const int tid = threadIdx.x;
    const int tx = tid & 15;    // col group: cols tx + 16*j
    const int ty = tid >> 4;    // row group: rows ty + 16*i

    // stage X tile (BM x DIM) once: 1024 float4, 4 per thread, coalesced
    #pragma unroll
    for (int u = 0; u < (BM * DIM / 4) / 256; u++) {
        int e = u * 256 + tid;
        int r = e >> 3;           // 8 float4 per row
        int c = (e & 7) * 4;
        float4 v = *(const float4*)(X + (size_t)(row0 + r) * DIM + c);
        *(float4*)&sx[r][c] = v;
    }

    float m_run[TM], s_run[TM];
    #pragma unroll
    for (int i = 0; i < TM; i++) { m_run[i] = -INFINITY; s_run[i] = 0.0f; }

    for (int k0 = 0; k0 < NPT; k0 += BK) {
        __syncthreads();   // previous tile fully consumed (also covers sx staging)
        #pragma unroll
        for (int u = 0; u < (BK * DIM / 4) / 256; u++) {
            int e = u * 256 + tid;
            int r = e >> 3;
            int c = (e & 7) * 4;
            float4 v = *(const float4*)(Y + (size_t)(k0 + r) * DIM + c);
            *(float4*)&sy[r][c] = v;
        }
        if (tid < BK) {
            int k = k0 + tid;
            st[tid] = pot[k] + logw[k] - qY[k];
        }
        __syncthreads();

        float acc[TM][TN];
        #pragma unroll
        for (int i = 0; i < TM; i++)
            #pragma unroll
            for (int j = 0; j < TN; j++) acc[i][j] = 0.0f;

        #pragma unroll
        for (int d = 0; d < DIM; d += 4) {
            float4 xa[TM], ya[TN];
            #pragma unroll
            for (int i = 0; i < TM; i++) xa[i] = *(const float4*)&sx[ty + 16 * i][d];
            #pragma unroll
            for (int j = 0; j < TN; j++) ya[j] = *(const float4*)&sy[tx + 16 * j][d];
            #pragma unroll
            for (int i = 0; i < TM; i++)
                #pragma unroll
                for (int j = 0; j < TN; j++) {
                    acc[i][j] = fmaf(xa[i].x, ya[j].x, acc[i][j]);
                    acc[i][j] = fmaf(xa[i].y, ya[j].y, acc[i][j]);
                    acc[i][j] = fmaf(xa[i].z, ya[j].z, acc[i][j]);
                    acc[i][j] = fmaf(xa[i].w, ya[j].w, acc[i][j]);
                }
        }

        float tj[TN];
        #pragma unroll
        for (int j = 0; j < TN; j++) tj[j] = st[tx + 16 * j];

        #pragma unroll
        for (int i = 0; i < TM; i++) {
            float v0 = acc[i][0] + tj[0];
            float v1 = acc[i][1] + tj[1];
            float v2 = acc[i][2] + tj[2];
            float v3 = acc[i][3] + tj[3];
            float mx = fmaxf(fmaxf(v0, v1), fmaxf(v2, v3));
            float mn = fmaxf(m_run[i], mx);
            float sc = __expf(m_run[i] - mn);   // exp(-inf)=0 handles first tile
            s_run[i] = s_run[i] * sc
                     + __expf(v0 - mn) + __expf(v1 - mn)
                     + __expf(v2 - mn) + __expf(v3 - mn);
            m_run[i] = mn;
        }
    }

    #pragma unroll
    for (int i = 0; i < TM; i++) {
        red_m[ty + 16 * i][tx] = m_run[i];
        red_s[ty + 16 * i][tx] = s_run[i];
    }
    __syncthreads();

    if (tid < BM) {
        float m = -INFINITY;
        #pragma unroll
        for (int j = 0; j < 16; j++) m = fmaxf(m, red_m[tid][j]);
        float s = 0.0f;
        #pragma unroll
        for (int j = 0; j < 16; j++) s += red_s[tid][j] * __expf(red_m[tid][j] - m);
        float lse = m + __logf(s);
        int l = row0 + tid;
        float val = qX[l] - lse;
        if (args.average) val = 0.5f * (cs.prev[(size_t)batch * NPT + l] + val);
        cs.out[(size_t)batch * NPT + l] = val;
    }
}

__global__ __launch_bounds__(256) void init_kernel(
        const float* __restrict__ x, const float* __restrict__ a,
        const float* __restrict__ y, const float* __restrict__ b,
        float* __restrict__ log_a, float* __restrict__ log_b,
        float* __restrict__ qx, float* __restrict__ qy,
        float* __restrict__ f, float* __restrict__ g,
        float* __restrict__ fx, float* __restrict__ fy) {
    int idx = blockIdx.x * 256 + threadIdx.x;
    if (idx >= BATCH * NPT) return;
    log_a[idx] = __logf(a[idx]);
    log_b[idx] = __logf(b[idx]);
    float sx = 0.f, sy = 0.f;
    const float* xp = x + (size_t)idx * DIM;
    const float* yp = y + (size_t)idx * DIM;
    #pragma unroll
    for (int d = 0; d < DIM; d += 4) {
        float4 vx = *(const float4*)(xp + d);
        float4 vy = *(const float4*)(yp + d);
        sx += vx.x * vx.x + vx.y * vx.y + vx.z * vx.z + vx.w * vx.w;
        sy += vy.x * vy.x + vy.y * vy.y + vy.z * vy.z + vy.w * vy.w;
    }
    qx[idx] = 0.5f * sx;
    qy[idx] = 0.5f * sy;
    f[idx] = 0.f; g[idx] = 0.f; fx[idx] = 0.f; fy[idx] = 0.f;
}

__global__ __launch_bounds__(256) void reduce_kernel(
        const float* __restrict__ a, const float* __restrict__ b,
        const float* __restrict__ ctA, const float* __restrict__ ctB,
        const float* __restrict__ ctX, const float* __restrict__ ctY,
        float* __restrict__ out) {
    float acc = 0.f;
    for (int idx = threadIdx.x; idx < BATCH * NPT; idx += 256) {
        acc += a[idx] * (ctA[idx] - ctX[idx]) + b[idx] * (ctB[idx] - ctY[idx]);
    }
    #pragma unroll
    for (int off = 32; off > 0; off >>= 1) acc += __shfl_down(acc, off, 64);
    __shared__ float sm[4];
    if ((threadIdx.x & 63) == 0) sm[threadIdx.x >> 6] = acc;
    __syncthreads();
    if (threadIdx.x == 0) out[0] = (sm[0] + sm[1] + sm[2] + sm[3]) / (float)BATCH;
}

extern "C" void kernel_launch(void* const* d_in, const int* in_sizes, int n_in,
                              void* d_out, int out_size, void* d_ws, size_t ws_size,
                              hipStream_t stream) {
    const float* x = (const float*)d_in[0];
    const float* a = (const float*)d_in[1];
    const float* y = (const float*)d_in[2];
    const float* b = (const float*)d_in[3];
    float* out = (float*)d_out;

    const size_t BN = (size_t)BATCH * NPT;
    float* ws = (float*)d_ws;
    float* log_a = ws + 0 * BN;
    float* log_b = ws + 1 * BN;
    float* qx    = ws + 2 * BN;
    float* qy    = ws + 3 * BN;
    float* fbuf[2]  = { ws + 4 * BN,  ws + 5 * BN };
    float* gbuf[2]  = { ws + 6 * BN,  ws + 7 * BN };
    float* fxbuf[2] = { ws + 8 * BN,  ws + 9 * BN };
    float* fybuf[2] = { ws + 10 * BN, ws + 11 * BN };
    float* ctA = ws + 12 * BN;
    float* ctB = ws + 13 * BN;
    float* ctX = ws + 14 * BN;
    float* ctY = ws + 15 * BN;

    init_kernel<<<(BATCH * NPT + 255) / 256, 256, 0, stream>>>(
        x, a, y, b, log_a, log_b, qx, qy, fbuf[0], gbuf[0], fxbuf[0], fybuf[0]);

    dim3 grid(NPT / BM, 4, BATCH);
    int cur = 0;
    for (int it = 0; it < 10; it++) {
        CtArgs ar;
        ar.average = 1;
        // fn = ct(g, log_b, kxy); out averaged with f_old
        ar.s[0].X = x;  ar.s[0].Y = y;  ar.s[0].pot = gbuf[cur];  ar.s[0].logw = log_b;
        ar.s[0].qX = qx; ar.s[0].qY = qy; ar.s[0].prev = fbuf[cur]; ar.s[0].out = fbuf[1 - cur];
        // gn = ct(f, log_a, kyx)
        ar.s[1].X = y;  ar.s[1].Y = x;  ar.s[1].pot = fbuf[cur];  ar.s[1].logw = log_a;
        ar.s[1].qX = qy; ar.s[1].qY = qx; ar.s[1].prev = gbuf[cur]; ar.s[1].out = gbuf[1 - cur];
        // sym x: ct(fx, log_a, kxx)
        ar.s[2].X = x;  ar.s[2].Y = x;  ar.s[2].pot = fxbuf[cur]; ar.s[2].logw = log_a;
        ar.s[2].qX = qx; ar.s[2].qY = qx; ar.s[2].prev = fxbuf[cur]; ar.s[2].out = fxbuf[1 - cur];
        // sym y: ct(fy, log_b, kyy)
        ar.s[3].X = y;  ar.s[3].Y = y;  ar.s[3].pot = fybuf[cur]; ar.s[3].logw = log_b;
        ar.s[3].qX = qy; ar.s[3].qY = qy; ar.s[3].prev = fybuf[cur]; ar.s[3].out = fybuf[1 - cur];
        ct_kernel<<<grid, 256, 0, stream>>>(ar);
        cur ^= 1;
    }

    CtArgs fin;
    fin.average = 0;
    // f~ = ct(g, log_b, kxy) -> dot with a
    fin.s[0].X = x; fin.s[0].Y = y; fin.s[0].pot = gbuf[cur]; fin.s[0].logw = log_b;
    fin.s[0].qX = qx; fin.s[0].qY = qy; fin.s[0].prev = nullptr; fin.s[0].out = ctA;
    // g~ = ct(f, log_a, kyx) -> dot with b
    fin.s[1].X = y; fin.s[1].Y = x; fin.s[1].pot = fbuf[cur]; fin.s[1].logw = log_a;
    fin.s[1].qX = qy; fin.s[1].qY = qx; fin.s[1].prev = nullptr; fin.s[1].out = ctB;
    // ent_x term: ct(fx, log_a, kxx) -> dot with a
    fin.s[2].X = x; fin.s[2].Y = x; fin.s[2].pot = fxbuf[cur]; fin.s[2].logw = log_a;
    fin.s[2].qX = qx; fin.s[2].qY = qx; fin.s[2].prev = nullptr; fin.s[2].out = ctX;
    // ent_y term: ct(fy, log_b, kyy) -> dot with b
    fin.s[3].X = y; fin.s[3].Y = y; fin.s[3].pot = fybuf[cur]; fin.s[3].logw = log_b;
    fin.s[3].qX = qy; fin.s[3].qY = qy; fin.s[3].prev = nullptr; fin.s[3].out = ctY;
    ct_kernel<<<grid, 256, 0, stream>>>(fin);

    reduce_kernel<<<1, 256, 0, stream>>>(a, b, ctA, ctB, ctX, ctY, out);
}

// Round 2
// 639.449 us; speedup vs baseline: 2.7135x; 2.7135x over previous
//
#include <hip/hip_runtime.h>
#include <math.h>

#define BATCH 8
#define NPT   2048
#define DIM   32
#define ROWS_PER_WAVE 32     // 2 strips of 16
#define WAVES 4
#define COLS_PER_WAVE (NPT / WAVES)   // 512
#define NCHUNK (COLS_PER_WAVE / 64)   // 8 chunks of 4 col-tiles

typedef __attribute__((ext_vector_type(8))) short short8;
typedef __attribute__((ext_vector_type(4))) float floatx4;
typedef unsigned short ushort_t;
typedef unsigned int uint_t;

__device__ __forceinline__ ushort_t f2bf(float v) {
    uint_t u = __float_as_uint(v);
    uint_t r = (u + 0x7FFFu + ((u >> 16) & 1u)) >> 16;
    return (ushort_t)r;
}
__device__ __forceinline__ float bf2f(ushort_t h) {
    return __uint_as_float(((uint_t)h) << 16);
}

struct CtSet {
    const ushort_t* Xh;  // rows side hi  [BATCH][NPT][DIM] bf16 bits
    const ushort_t* Xl;  // rows side lo
    const ushort_t* Yh;  // cols side hi
    const ushort_t* Yl;  // cols side lo
    const float* pot;    // potential on cols [BATCH][NPT]
    const float* cw;     // logw - qY on cols (iteration-invariant)
    const float* qX;     // 0.5*||row||^2
    const float* prev;   // previous row potential (averaging), may be null
    float* out;          // [BATCH][NPT]
};
struct CtArgs { CtSet s[4]; int average; };

// out[l] = qX[l] - lse_k( x_l . y_k + pot[k] + cw[k] ), opt 0.5*(prev + .)
__global__ __launch_bounds__(256, 3) void ct_kernel(CtArgs args) {
    const CtSet cs = args.s[blockIdx.y];
    const int batch = blockIdx.z;
    const int row0 = blockIdx.x * ROWS_PER_WAVE;

    const int tid  = threadIdx.x;
    const int w    = tid >> 6;
    const int lane = tid & 63;
    const int n    = lane & 15;
    const int quad = lane >> 4;
    const int qk   = quad * 8;

    const size_t pbase = (size_t)batch * NPT * DIM;
    const size_t vbase = (size_t)batch * NPT;
    const ushort_t* __restrict__ Xh = cs.Xh + pbase;
    const ushort_t* __restrict__ Xl = cs.Xl + pbase;
    const ushort_t* __restrict__ Yh = cs.Yh + pbase;
    const ushort_t* __restrict__ Yl = cs.Yl + pbase;
    const float* __restrict__ pot = cs.pot + vbase;
    const float* __restrict__ cw  = cs.cw  + vbase;
    const float* __restrict__ qX  = cs.qX  + vbase;

    // A fragments: 2 strips x (hi,lo); A[m=lane&15][k=quad*8+j] = X[row][dim]
    short8 ah[2], al[2];
    #pragma unroll
    for (int s = 0; s < 2; s++) {
        size_t off = (size_t)(row0 + s * 16 + n) * DIM + qk;
        ah[s] = *(const short8*)(Xh + off);
        al[s] = *(const short8*)(Xl + off);
    }

    float mr[2][4], sr[2][4];
    #pragma unroll
    for (int s = 0; s < 2; s++)
        #pragma unroll
        for (int r = 0; r < 4; r++) { mr[s][r] = -INFINITY; sr[s][r] = 0.0f; }

    const int colbase = w * COLS_PER_WAVE;

    #pragma unroll 1
    for (int ch = 0; ch < NCHUNK; ch++) {
        const int cb = colbase + ch * 64;
        short8 bh[4], bl[4];
        float tv[4];
        #pragma unroll
        for (int tt = 0; tt < 4; tt++) {
            int cp = cb + tt * 16 + n;
            size_t off = (size_t)cp * DIM + qk;
            bh[tt] = *(const short8*)(Yh + off);
            bl[tt] = *(const short8*)(Yl + off);
            tv[tt] = pot[cp] + cw[cp];
        }

        floatx4 acc[2][4];
        #pragma unroll
        for (int s = 0; s < 2; s++)
            #pragma unroll
            for (int tt = 0; tt < 4; tt++)
                acc[s][tt] = (floatx4){0.f, 0.f, 0.f, 0.f};

        #pragma unroll
        for (int tt = 0; tt < 4; tt++)
            #pragma unroll
            for (int s = 0; s < 2; s++) {
                acc[s][tt] = __builtin_amdgcn_mfma_f32_16x16x32_bf16(ah[s], bh[tt], acc[s][tt], 0, 0, 0);
                acc[s][tt] = __builtin_amdgcn_mfma_f32_16x16x32_bf16(ah[s], bl[tt], acc[s][tt], 0, 0, 0);
                acc[s][tt] = __builtin_amdgcn_mfma_f32_16x16x32_bf16(al[s], bh[tt], acc[s][tt], 0, 0, 0);
            }

        // online softmax, one rescale per 4 columns per row
        #pragma unroll
        for (int s = 0; s < 2; s++)
            #pragma unroll
            for (int r = 0; r < 4; r++) {
                float v0 = acc[s][0][r] + tv[0];
                float v1 = acc[s][1][r] + tv[1];
                float v2 = acc[s][2][r] + tv[2];
                float v3 = acc[s][3][r] + tv[3];
                float cmax = fmaxf(fmaxf(v0, v1), fmaxf(v2, v3));
                float mn = fmaxf(mr[s][r], cmax);
                float sc = __expf(mr[s][r] - mn);   // exp(-inf)=0 first chunk
                sr[s][r] = sr[s][r] * sc
                         + __expf(v0 - mn) + __expf(v1 - mn)
                         + __expf(v2 - mn) + __expf(v3 - mn);
                mr[s][r] = mn;
            }
    }

    // combine across the 16 col-lanes within each quad, then across waves via LDS
    __shared__ float lm[ROWS_PER_WAVE][WAVES];
    __shared__ float ls[ROWS_PER_WAVE][WAVES];

    #pragma unroll
    for (int s = 0; s < 2; s++)
        #pragma unroll
        for (int r = 0; r < 4; r++) {
            float m = mr[s][r], sv = sr[s][r];
            #pragma unroll
            for (int mask = 1; mask < 16; mask <<= 1) {
                float mo = __shfl_xor(m, mask, 64);
                float so = __shfl_xor(sv, mask, 64);
                float mn = fmaxf(m, mo);
                sv = sv * __expf(m - mn) + so * __expf(mo - mn);
                m = mn;
            }
            if (n == 0) {
                int rl = s * 16 + quad * 4 + r;
                lm[rl][w] = m;
                ls[rl][w] = sv;
            }
        }
    __syncthreads();

    if (tid < ROWS_PER_WAVE) {
        float m = fmaxf(fmaxf(lm[tid][0], lm[tid][1]), fmaxf(lm[tid][2], lm[tid][3]));
        float sv = ls[tid][0] * __expf(lm[tid][0] - m)
                 + ls[tid][1] * __expf(lm[tid][1] - m)
                 + ls[tid][2] * __expf(lm[tid][2] - m)
                 + ls[tid][3] * __expf(lm[tid][3] - m);
        float lse = m + __logf(sv);
        int l = row0 + tid;
        float val = qX[l] - lse;
        if (args.average) val = 0.5f * (cs.prev[vbase + l] + val);
        cs.out[vbase + l] = val;
    }
}

__global__ __launch_bounds__(256) void init_kernel(
        const float* __restrict__ x, const float* __restrict__ a,
        const float* __restrict__ y, const float* __restrict__ b,
        float* __restrict__ c_x, float* __restrict__ c_y,
        float* __restrict__ qx, float* __restrict__ qy,
        ushort_t* __restrict__ xh, ushort_t* __restrict__ xl,
        ushort_t* __restrict__ yh, ushort_t* __restrict__ yl,
        float* __restrict__ f, float* __restrict__ g,
        float* __restrict__ fx, float* __restrict__ fy) {
    int idx = blockIdx.x * 256 + threadIdx.x;
    if (idx >= BATCH * NPT) return;
    const float* xp = x + (size_t)idx * DIM;
    const float* yp = y + (size_t)idx * DIM;
    uint_t* xhp = (uint_t*)xh + (size_t)idx * (DIM / 2);
    uint_t* xlp = (uint_t*)xl + (size_t)idx * (DIM / 2);
    uint_t* yhp = (uint_t*)yh + (size_t)idx * (DIM / 2);
    uint_t* ylp = (uint_t*)yl + (size_t)idx * (DIM / 2);
    float sx = 0.f, sy = 0.f;
    #pragma unroll
    for (int d = 0; d < DIM; d += 2) {
        float v0 = xp[d], v1 = xp[d + 1];
        sx += v0 * v0 + v1 * v1;
        ushort_t h0 = f2bf(v0), h1 = f2bf(v1);
        xhp[d / 2] = (uint_t)h0 | ((uint_t)h1 << 16);
        ushort_t l0 = f2bf(v0 - bf2f(h0)), l1 = f2bf(v1 - bf2f(h1));
        xlp[d / 2] = (uint_t)l0 | ((uint_t)l1 << 16);
        float u0 = yp[d], u1 = yp[d + 1];
        sy += u0 * u0 + u1 * u1;
        ushort_t g0 = f2bf(u0), g1 = f2bf(u1);
        yhp[d / 2] = (uint_t)g0 | ((uint_t)g1 << 16);
        ushort_t m0 = f2bf(u0 - bf2f(g0)), m1 = f2bf(u1 - bf2f(g1));
        ylp[d / 2] = (uint_t)m0 | ((uint_t)m1 << 16);
    }
    float qxv = 0.5f * sx, qyv = 0.5f * sy;
    qx[idx] = qxv; qy[idx] = qyv;
    c_x[idx] = __logf(a[idx]) - qxv;
    c_y[idx] = __logf(b[idx]) - qyv;
    f[idx] = 0.f; g[idx] = 0.f; fx[idx] = 0.f; fy[idx] = 0.f;
}

__global__ __launch_bounds__(256) void reduce_kernel(
        const float* __restrict__ a, const float* __restrict__ b,
        const float* __restrict__ ctA, const float* __restrict__ ctB,
        const float* __restrict__ ctX, const float* __restrict__ ctY,
        float* __restrict__ out) {
    float acc = 0.f;
    for (int idx = threadIdx.x; idx < BATCH * NPT; idx += 256) {
        acc += a[idx] * (ctA[idx] - ctX[idx]) + b[idx] * (ctB[idx] - ctY[idx]);
    }
    #pragma unroll
    for (int off = 32; off > 0; off >>= 1) acc += __shfl_down(acc, off, 64);
    __shared__ float sm[4];
    if ((threadIdx.x & 63) == 0) sm[threadIdx.x >> 6] = acc;
    __syncthreads();
    if (threadIdx.x == 0) out[0] = (sm[0] + sm[1] + sm[2] + sm[3]) / (float)BATCH;
}

extern "C" void kernel_launch(void* const* d_in, const int* in_sizes, int n_in,
                              void* d_out, int out_size, void* d_ws, size_t ws_size,
                              hipStream_t stream) {
    const float* x = (const float*)d_in[0];
    const float* a = (const float*)d_in[1];
    const float* y = (const float*)d_in[2];
    const float* b = (const float*)d_in[3];
    float* out = (float*)d_out;

    const size_t BN = (size_t)BATCH * NPT;
    float* ws = (float*)d_ws;
    float* c_x = ws + 0 * BN;   // log_a - qx
    float* c_y = ws + 1 * BN;   // log_b - qy
    float* qx  = ws + 2 * BN;
    float* qy  = ws + 3 * BN;
    float* fbuf[2]  = { ws + 4 * BN,  ws + 5 * BN };
    float* gbuf[2]  = { ws + 6 * BN,  ws + 7 * BN };
    float* fxbuf[2] = { ws + 8 * BN,  ws + 9 * BN };
    float* fybuf[2] = { ws + 10 * BN, ws + 11 * BN };
    float* ctA = ws + 12 * BN;
    float* ctB = ws + 13 * BN;
    float* ctX = ws + 14 * BN;
    float* ctY = ws + 15 * BN;
    ushort_t* xh = (ushort_t*)(ws + 16 * BN);
    ushort_t* xl = xh + BN * DIM;
    ushort_t* yh = xl + BN * DIM;
    ushort_t* yl = yh + BN * DIM;

    init_kernel<<<(int)((BN + 255) / 256), 256, 0, stream>>>(
        x, a, y, b, c_x, c_y, qx, qy, xh, xl, yh, yl,
        fbuf[0], gbuf[0], fxbuf[0], fybuf[0]);

    dim3 grid(NPT / ROWS_PER_WAVE, 4, BATCH);
    int cur = 0;
    for (int it = 0; it < 10; it++) {
        CtArgs ar;
        ar.average = 1;
        // fn = ct(g, log_b, kxy)
        ar.s[0] = { xh, xl, yh, yl, gbuf[cur],  c_y, qx, fbuf[cur],  fbuf[1 - cur] };
        // gn = ct(f, log_a, kyx)
        ar.s[1] = { yh, yl, xh, xl, fbuf[cur],  c_x, qy, gbuf[cur],  gbuf[1 - cur] };
        // sym x: ct(fx, log_a, kxx)
        ar.s[2] = { xh, xl, xh, xl, fxbuf[cur], c_x, qx, fxbuf[cur], fxbuf[1 - cur] };
        // sym y: ct(fy, log_b, kyy)
        ar.s[3] = { yh, yl, yh, yl, fybuf[cur], c_y, qy, fybuf[cur], fybuf[1 - cur] };
        ct_kernel<<<grid, 256, 0, stream>>>(ar);
        cur ^= 1;
    }

    CtArgs fin;
    fin.average = 0;
    fin.s[0] = { xh, xl, yh, yl, gbuf[cur],  c_y, qx, nullptr, ctA };
    fin.s[1] = { yh, yl, xh, xl, fbuf[cur],  c_x, qy, nullptr, ctB };
    fin.s[2] = { xh, xl, xh, xl, fxbuf[cur], c_x, qx, nullptr, ctX };
    fin.s[3] = { yh, yl, yh, yl, fybuf[cur], c_y, qy, nullptr, ctY };
    ct_kernel<<<grid, 256, 0, stream>>>(fin);

    reduce_kernel<<<1, 256, 0, stream>>>(a, b, ctA, ctB, ctX, ctY, out);
}

// Round 5
// 552.076 us; speedup vs baseline: 3.1429x; 1.1583x over previous
//
#include <hip/hip_runtime.h>
#include <math.h>

#define BATCH 8
#define NPT   2048
#define DIM   32
#define RPB   32                      // rows per block (2 strips of 16)
#define WAVES 4
#define CPW   (NPT / WAVES)           // 512 cols per wave
#define NCHUNK (CPW / 64)             // 8 chunks of 4 col-tiles
#define L2E   1.44269504088896f
#define BIAS2   96.0f                 // log2-domain bias: u' = 96 + log2e*(v-M0) <= 96
#define BIASLN  66.54212933375474f    // 96*ln2
#define BN    (BATCH * NPT)

typedef __attribute__((ext_vector_type(8))) short short8;
typedef __attribute__((ext_vector_type(4))) float floatx4;
typedef unsigned short u16;
typedef unsigned int u32;

__device__ __forceinline__ u16 f2bf(float v) {
    u32 u = __float_as_uint(v);
    return (u16)((u + 0x7FFFu + ((u >> 16) & 1u)) >> 16);
}
__device__ __forceinline__ float bf2f(u16 h) { return __uint_as_float(((u32)h) << 16); }
__device__ __forceinline__ float exp2v(float x) { return __builtin_amdgcn_exp2f(x); }

struct CtSet {
    const u16* Ah;  const u16* Al;    // row-side plain split bf16 [BATCH][NPT][DIM]
    const u16* Bh;  const u16* Bl;    // col-side log2e-scaled split bf16
    const float* tls;     // log2e*(pot+cw) on cols [BATCH][NPT]
    const float* qX;      // 0.5*||row||^2
    const float* normR;   // row norms
    const float* cn;      // per-batch max col norm (pre-offset by side) [BATCH]
    const float* bmIn;    // [BATCH][64] per-block max of (pot+cw) on cols
    const float* cwNext;  // cw paired with out when out is later used as cols
    const float* prev;    // previous row potential (averaging)
    float* out;           // [BATCH][NPT]
    float* tlsOut;        // log2e*(out+cwNext)
    float* bmOut;         // [BATCH][64] blockmax of (out+cwNext)
};
struct CtArgs { CtSet s[4]; int average; };

// out[l] = qX[l] - lse_k( x_l . y_k + pot[k] + cw[k] ), opt 0.5*(prev + .)
__global__ __launch_bounds__(256, 3) void ct_kernel(CtArgs args) {
    const CtSet cs = args.s[blockIdx.y];
    const int batch = blockIdx.z;
    const int row0 = blockIdx.x * RPB;
    const int tid  = threadIdx.x;
    const int w = tid >> 6, lane = tid & 63, n = lane & 15, quad = lane >> 4;
    const int qk = quad * 8;
    const size_t pbase = (size_t)batch * NPT * DIM;
    const size_t vbase = (size_t)batch * NPT;

    __shared__ float sT;
    __shared__ float lsum[RPB][WAVES];

    // Tmax = max_k (pot_k + cw_k): reduce 64 producer block-maxes
    if (tid < 64) {
        float v = cs.bmIn[batch * 64 + tid];
        #pragma unroll
        for (int m = 1; m < 64; m <<= 1) v = fmaxf(v, __shfl_xor(v, m, 64));
        if (tid == 0) sT = v;
    }

    const u16* __restrict__ Ah = cs.Ah + pbase;
    const u16* __restrict__ Al = cs.Al + pbase;
    const u16* __restrict__ Bh = cs.Bh + pbase;
    const u16* __restrict__ Bl = cs.Bl + pbase;
    const float* __restrict__ tls = cs.tls + vbase;

    // A fragments: A[m=lane&15][k=quad*8+j] = X[row][dim]
    short8 ah[2], al[2];
    #pragma unroll
    for (int s = 0; s < 2; s++) {
        size_t off = (size_t)(row0 + s * 16 + n) * DIM + qk;
        ah[s] = *(const short8*)(Ah + off);
        al[s] = *(const short8*)(Al + off);
    }

    __syncthreads();
    const float Tmax = sT;
    const float cnv = cs.cn[batch];
    float M0s[2][4];   // log2e*M0 - BIAS2 (subtracted in acc init)
    #pragma unroll
    for (int s = 0; s < 2; s++)
        #pragma unroll
        for (int r = 0; r < 4; r++) {
            int row = row0 + s * 16 + quad * 4 + r;
            M0s[s][r] = L2E * (cs.normR[vbase + row] * cnv + Tmax) - BIAS2;
        }

    float sum[2][4];
    #pragma unroll
    for (int s = 0; s < 2; s++)
        #pragma unroll
        for (int r = 0; r < 4; r++) sum[s][r] = 0.0f;

    const int colbase = w * CPW;

    #pragma unroll 1
    for (int ch = 0; ch < NCHUNK; ch++) {
        const int cb = colbase + ch * 64;
        short8 bh[4], bl[4];
        float tvs[4];
        #pragma unroll
        for (int tt = 0; tt < 4; tt++) {
            int cp = cb + tt * 16 + n;
            size_t off = (size_t)cp * DIM + qk;
            bh[tt] = *(const short8*)(Bh + off);
            bl[tt] = *(const short8*)(Bl + off);
            tvs[tt] = tls[cp];
        }

        floatx4 acc[2][4];
        #pragma unroll
        for (int s = 0; s < 2; s++)
            #pragma unroll
            for (int tt = 0; tt < 4; tt++)
                acc[s][tt] = (floatx4){tvs[tt] - M0s[s][0], tvs[tt] - M0s[s][1],
                                       tvs[tt] - M0s[s][2], tvs[tt] - M0s[s][3]};

        #pragma unroll
        for (int tt = 0; tt < 4; tt++)
            #pragma unroll
            for (int s = 0; s < 2; s++) {
                acc[s][tt] = __builtin_amdgcn_mfma_f32_16x16x32_bf16(ah[s], bh[tt], acc[s][tt], 0, 0, 0);
                acc[s][tt] = __builtin_amdgcn_mfma_f32_16x16x32_bf16(ah[s], bl[tt], acc[s][tt], 0, 0, 0);
                acc[s][tt] = __builtin_amdgcn_mfma_f32_16x16x32_bf16(al[s], bh[tt], acc[s][tt], 0, 0, 0);
            }

        // u' = 96 + log2e*(v - M0) in [~ -126, 96]: sum += 2^u', no max tracking
        #pragma unroll
        for (int s = 0; s < 2; s++)
            #pragma unroll
            for (int r = 0; r < 4; r++) {
                float e0 = exp2v(acc[s][0][r]);
                float e1 = exp2v(acc[s][1][r]);
                float e2 = exp2v(acc[s][2][r]);
                float e3 = exp2v(acc[s][3][r]);
                sum[s][r] += (e0 + e1) + (e2 + e3);
            }
    }

    // sum across 16 col-lanes in each quad, then across waves via LDS
    #pragma unroll
    for (int s = 0; s < 2; s++)
        #pragma unroll
        for (int r = 0; r < 4; r++) {
            float v = sum[s][r];
            #pragma unroll
            for (int m = 1; m < 16; m <<= 1) v += __shfl_xor(v, m, 64);
            if (n == 0) lsum[s * 16 + quad * 4 + r][w] = v;
        }
    __syncthreads();

    if (tid < RPB) {
        float T = (lsum[tid][0] + lsum[tid][1]) + (lsum[tid][2] + lsum[tid][3]);
        int l = row0 + tid;
        float M0 = cs.normR[vbase + l] * cnv + Tmax;
        float lse = M0 + __logf(T) - BIASLN;
        float val = cs.qX[vbase + l] - lse;
        if (args.average) val = 0.5f * (cs.prev[vbase + l] + val);
        cs.out[vbase + l] = val;
        float tc = val + cs.cwNext[vbase + l];
        cs.tlsOut[vbase + l] = L2E * tc;
        float bm = tc;
        #pragma unroll
        for (int m = 1; m < 32; m <<= 1) bm = fmaxf(bm, __shfl_xor(bm, m, 32));
        if (tid == 0) cs.bmOut[batch * 64 + blockIdx.x] = bm;
    }
}

struct InitArgs {
    const float *x, *a, *y, *b;
    float *c_x, *c_y, *qx, *qy, *nx, *ny;
    u16 *xh, *xl, *yh, *yl, *xsh, *xsl, *ysh, *ysl;
    float *f0, *g0, *fx0, *fy0;
    float *tlsF0, *tlsG0, *tlsFx0, *tlsFy0;
    float *bmF0, *bmG0, *bmFx0, *bmFy0;
};

__global__ __launch_bounds__(256) void init_kernel(InitArgs ia) {
    int idx = blockIdx.x * 256 + threadIdx.x;
    if (idx >= BN) return;
    const float* xp = ia.x + (size_t)idx * DIM;
    const float* yp = ia.y + (size_t)idx * DIM;
    u32* xhp  = (u32*)ia.xh  + (size_t)idx * (DIM / 2);
    u32* xlp  = (u32*)ia.xl  + (size_t)idx * (DIM / 2);
    u32* yhp  = (u32*)ia.yh  + (size_t)idx * (DIM / 2);
    u32* ylp  = (u32*)ia.yl  + (size_t)idx * (DIM / 2);
    u32* xshp = (u32*)ia.xsh + (size_t)idx * (DIM / 2);
    u32* xslp = (u32*)ia.xsl + (size_t)idx * (DIM / 2);
    u32* yshp = (u32*)ia.ysh + (size_t)idx * (DIM / 2);
    u32* yslp = (u32*)ia.ysl + (size_t)idx * (DIM / 2);
    float sx = 0.f, sy = 0.f;
    #pragma unroll
    for (int d = 0; d < DIM; d += 2) {
        float v0 = xp[d], v1 = xp[d + 1];
        sx += v0 * v0 + v1 * v1;
        u16 h0 = f2bf(v0), h1 = f2bf(v1);
        xhp[d / 2] = (u32)h0 | ((u32)h1 << 16);
        xlp[d / 2] = (u32)f2bf(v0 - bf2f(h0)) | ((u32)f2bf(v1 - bf2f(h1)) << 16);
        float w0 = L2E * v0, w1 = L2E * v1;
        u16 sh0 = f2bf(w0), sh1 = f2bf(w1);
        xshp[d / 2] = (u32)sh0 | ((u32)sh1 << 16);
        xslp[d / 2] = (u32)f2bf(w0 - bf2f(sh0)) | ((u32)f2bf(w1 - bf2f(sh1)) << 16);

        float u0 = yp[d], u1 = yp[d + 1];
        sy += u0 * u0 + u1 * u1;
        u16 g0 = f2bf(u0), g1 = f2bf(u1);
        yhp[d / 2] = (u32)g0 | ((u32)g1 << 16);
        ylp[d / 2] = (u32)f2bf(u0 - bf2f(g0)) | ((u32)f2bf(u1 - bf2f(g1)) << 16);
        float z0 = L2E * u0, z1 = L2E * u1;
        u16 th0 = f2bf(z0), th1 = f2bf(z1);
        yshp[d / 2] = (u32)th0 | ((u32)th1 << 16);
        yslp[d / 2] = (u32)f2bf(z0 - bf2f(th0)) | ((u32)f2bf(z1 - bf2f(th1)) << 16);
    }
    float qxv = 0.5f * sx, qyv = 0.5f * sy;
    ia.qx[idx] = qxv; ia.qy[idx] = qyv;
    ia.nx[idx] = sqrtf(sx); ia.ny[idx] = sqrtf(sy);
    float cxv = __logf(ia.a[idx]) - qxv;
    float cyv = __logf(ia.b[idx]) - qyv;
    ia.c_x[idx] = cxv; ia.c_y[idx] = cyv;
    ia.f0[idx] = 0.f; ia.g0[idx] = 0.f; ia.fx0[idx] = 0.f; ia.fy0[idx] = 0.f;
    ia.tlsF0[idx] = L2E * cxv; ia.tlsG0[idx] = L2E * cyv;
    ia.tlsFx0[idx] = L2E * cxv; ia.tlsFy0[idx] = L2E * cyv;
    // per-32-row blockmax of (0 + cw)
    float mx = cxv, my = cyv;
    #pragma unroll
    for (int m = 1; m < 32; m <<= 1) {
        mx = fmaxf(mx, __shfl_xor(mx, m, 32));
        my = fmaxf(my, __shfl_xor(my, m, 32));
    }
    if ((threadIdx.x & 31) == 0) {
        int g = idx >> 5;   // == batch*64 + blockx
        ia.bmF0[g] = mx; ia.bmFx0[g] = mx;
        ia.bmG0[g] = my; ia.bmFy0[g] = my;
    }
}

__global__ __launch_bounds__(256) void precomp_kernel(const float* __restrict__ qx,
                                                      const float* __restrict__ qy,
                                                      float* __restrict__ cn) {
    int side = blockIdx.x, batch = blockIdx.y;
    const float* q = side ? qy : qx;
    float m = 0.f;
    for (int k = threadIdx.x; k < NPT; k += 256) m = fmaxf(m, q[(size_t)batch * NPT + k]);
    #pragma unroll
    for (int mm = 1; mm < 64; mm <<= 1) m = fmaxf(m, __shfl_xor(m, mm, 64));
    __shared__ float sm[4];
    if ((threadIdx.x & 63) == 0) sm[threadIdx.x >> 6] = m;
    __syncthreads();
    if (threadIdx.x == 0) {
        float v = fmaxf(fmaxf(sm[0], sm[1]), fmaxf(sm[2], sm[3]));
        cn[side * BATCH + batch] = sqrtf(2.f * v);
    }
}

__global__ __launch_bounds__(256) void reduce_kernel(
        const float* __restrict__ a, const float* __restrict__ b,
        const float* __restrict__ ctA, const float* __restrict__ ctB,
        const float* __restrict__ ctX, const float* __restrict__ ctY,
        float* __restrict__ out) {
    float acc = 0.f;
    for (int idx = threadIdx.x; idx < BN; idx += 256) {
        acc += a[idx] * (ctA[idx] - ctX[idx]) + b[idx] * (ctB[idx] - ctY[idx]);
    }
    #pragma unroll
    for (int off = 32; off > 0; off >>= 1) acc += __shfl_down(acc, off, 64);
    __shared__ float sm[4];
    if ((threadIdx.x & 63) == 0) sm[threadIdx.x >> 6] = acc;
    __syncthreads();
    if (threadIdx.x == 0) out[0] = (sm[0] + sm[1] + sm[2] + sm[3]) / (float)BATCH;
}

extern "C" void kernel_launch(void* const* d_in, const int* in_sizes, int n_in,
                              void* d_out, int out_size, void* d_ws, size_t ws_size,
                              hipStream_t stream) {
    const float* x = (const float*)d_in[0];
    const float* a = (const float*)d_in[1];
    const float* y = (const float*)d_in[2];
    const float* b = (const float*)d_in[3];
    float* out = (float*)d_out;

    float* ws = (float*)d_ws;
    float* c_x = ws + 0 * BN;
    float* c_y = ws + 1 * BN;
    float* qx  = ws + 2 * BN;
    float* qy  = ws + 3 * BN;
    float* nx  = ws + 4 * BN;
    float* ny  = ws + 5 * BN;
    float* fb[2]  = { ws + 6 * BN,  ws + 7 * BN };
    float* gb[2]  = { ws + 8 * BN,  ws + 9 * BN };
    float* fxb[2] = { ws + 10 * BN, ws + 11 * BN };
    float* fyb[2] = { ws + 12 * BN, ws + 13 * BN };
    float* ctA = ws + 14 * BN;
    float* ctB = ws + 15 * BN;
    float* ctX = ws + 16 * BN;
    float* ctY = ws + 17 * BN;
    float* tlsF[2]  = { ws + 18 * BN, ws + 19 * BN };
    float* tlsG[2]  = { ws + 20 * BN, ws + 21 * BN };
    float* tlsFx[2] = { ws + 22 * BN, ws + 23 * BN };
    float* tlsFy[2] = { ws + 24 * BN, ws + 25 * BN };
    float* dummyT = ws + 26 * BN;
    float* small = ws + 27 * BN;
    float* bmF[2]  = { small + 0 * 512, small + 1 * 512 };
    float* bmG[2]  = { small + 2 * 512, small + 3 * 512 };
    float* bmFx[2] = { small + 4 * 512, small + 5 * 512 };
    float* bmFy[2] = { small + 6 * 512, small + 7 * 512 };
    float* dummyB = small + 8 * 512;
    float* cn = small + 9 * 512;   // [2][BATCH]
    u16* bf = (u16*)(small + 10 * 512);
    const size_t AS = (size_t)BN * DIM;
    u16* xh  = bf + 0 * AS; u16* xl  = bf + 1 * AS;
    u16* yh  = bf + 2 * AS; u16* yl  = bf + 3 * AS;
    u16* xsh = bf + 4 * AS; u16* xsl = bf + 5 * AS;
    u16* ysh = bf + 6 * AS; u16* ysl = bf + 7 * AS;

    InitArgs ia;
    ia.x = x; ia.a = a; ia.y = y; ia.b = b;
    ia.c_x = c_x; ia.c_y = c_y; ia.qx = qx; ia.qy = qy; ia.nx = nx; ia.ny = ny;
    ia.xh = xh; ia.xl = xl; ia.yh = yh; ia.yl = yl;
    ia.xsh = xsh; ia.xsl = xsl; ia.ysh = ysh; ia.ysl = ysl;
    ia.f0 = fb[0]; ia.g0 = gb[0]; ia.fx0 = fxb[0]; ia.fy0 = fyb[0];
    ia.tlsF0 = tlsF[0]; ia.tlsG0 = tlsG[0]; ia.tlsFx0 = tlsFx[0]; ia.tlsFy0 = tlsFy[0];
    ia.bmF0 = bmF[0]; ia.bmG0 = bmG[0]; ia.bmFx0 = bmFx[0]; ia.bmFy0 = bmFy[0];
    init_kernel<<<BN / 256, 256, 0, stream>>>(ia);
    precomp_kernel<<<dim3(2, BATCH), 256, 0, stream>>>(qx, qy, cn);

    dim3 grid(NPT / RPB, 4, BATCH);
    int cur = 0;
    for (int it = 0; it < 10; it++) {
        CtArgs ar;
        ar.average = 1;
        // set0: fn = ct(g, log_b, kxy): rows X, cols Y
        ar.s[0] = { xh, xl, ysh, ysl, tlsG[cur], qx, nx, cn + BATCH, bmG[cur], c_x,
                    fb[cur], fb[1 - cur], tlsF[1 - cur], bmF[1 - cur] };
        // set1: gn = ct(f, log_a, kyx): rows Y, cols X
        ar.s[1] = { yh, yl, xsh, xsl, tlsF[cur], qy, ny, cn, bmF[cur], c_y,
                    gb[cur], gb[1 - cur], tlsG[1 - cur], bmG[1 - cur] };
        // set2: sym x: rows X, cols X
        ar.s[2] = { xh, xl, xsh, xsl, tlsFx[cur], qx, nx, cn, bmFx[cur], c_x,
                    fxb[cur], fxb[1 - cur], tlsFx[1 - cur], bmFx[1 - cur] };
        // set3: sym y: rows Y, cols Y
        ar.s[3] = { yh, yl, ysh, ysl, tlsFy[cur], qy, ny, cn + BATCH, bmFy[cur], c_y,
                    fyb[cur], fyb[1 - cur], tlsFy[1 - cur], bmFy[1 - cur] };
        ct_kernel<<<grid, 256, 0, stream>>>(ar);
        cur ^= 1;
    }

    CtArgs fin;
    fin.average = 0;
    fin.s[0] = { xh, xl, ysh, ysl, tlsG[cur], qx, nx, cn + BATCH, bmG[cur], c_x,
                 fb[cur], ctA, dummyT, dummyB };
    fin.s[1] = { yh, yl, xsh, xsl, tlsF[cur], qy, ny, cn, bmF[cur], c_y,
                 gb[cur], ctB, dummyT, dummyB };
    fin.s[2] = { xh, xl, xsh, xsl, tlsFx[cur], qx, nx, cn, bmFx[cur], c_x,
                 fxb[cur], ctX, dummyT, dummyB };
    fin.s[3] = { yh, yl, ysh, ysl, tlsFy[cur], qy, ny, cn + BATCH, bmFy[cur], c_y,
                 fyb[cur], ctY, dummyT, dummyB };
    ct_kernel<<<grid, 256, 0, stream>>>(fin);

    reduce_kernel<<<1, 256, 0, stream>>>(a, b, ctA, ctB, ctX, ctY, out);
}